// Round 6
// baseline (8508.488 us; speedup 1.0000x reference)
//
#include <hip/hip_runtime.h>
#include <hip/hip_cooperative_groups.h>
#include <math.h>

namespace cg = cooperative_groups;

// B=4096 images, P=4096 pixels, F=1024 filters, 50 AdamW steps.
// Round 11: cut L2 traffic 2x. Evidence: R9 vs R10 identical dur (1865/1860us)
// across different schedules + Little's-law => throughput-bound on the Gblk
// stream (22.5 B/cy/CU, 13.8 TB/s chip = practical L2 ceiling, L1-hit 0%).
// Restructure: split F across block pairs. Block (rg,h) = 32 rows x 512 cols
// -> reads 1 MB of G/step (half). Partner act halves exchanged via global
// (32 KB/block/step, L3-resident, double-buffered) + one grid.sync()/step
// (hipLaunchCooperativeKernel, 256 blocks = 1/CU). Per-thread state stays
// 48 AGPR U/M/V + 16 acc (proven no-spill). Exchange copies raw bf16 bits,
// same math order -> bit-identical outputs.

typedef __bf16 bf16_t;
typedef __bf16 bf16x8 __attribute__((ext_vector_type(8)));
typedef __bf16 bf16x4 __attribute__((ext_vector_type(4)));
typedef float f32x4 __attribute__((ext_vector_type(4)));

__device__ __forceinline__ void async_ld16(const void* g, void* l) {
    __builtin_amdgcn_global_load_lds(
        (const __attribute__((address_space(1))) void*)g,
        (__attribute__((address_space(3))) void*)l, 16, 0, 0);
}

// AGPR stash: long-lived per-thread state in the accumulator half of the
// unified register file (arch half capped at 64 regs at 4 waves/EU).
__device__ __forceinline__ float ag_read(const float& a_) {
    float v;
    asm("v_accvgpr_read_b32 %0, %1" : "=v"(v) : "a"(a_));
    return v;
}
__device__ __forceinline__ void ag_write(float& a_, float v) {
    asm("v_accvgpr_write_b32 %0, %1" : "=a"(a_) : "v"(v));
}

__global__ void cvt_bf16(const float* __restrict__ x, bf16_t* __restrict__ y, long n) {
    long i = ((long)blockIdx.x * blockDim.x + threadIdx.x) * 4;
    if (i + 3 < n) {
        float4 f = *(const float4*)(x + i);
        bf16x4 o = { (bf16_t)f.x, (bf16_t)f.y, (bf16_t)f.z, (bf16_t)f.w };
        *(bf16x4*)(y + i) = o;
    }
}

// PhiT[f][p] = Phi[p][f], fp32 -> bf16.  Phi is [4096,1024].
__global__ void transpose_cvt(const float* __restrict__ src, bf16_t* __restrict__ dst) {
    __shared__ float tile[32][33];
    const int f0 = blockIdx.x * 32;
    const int p0 = blockIdx.y * 32;
    const int tx = threadIdx.x, ty = threadIdx.y;
    for (int r = ty; r < 32; r += 8)
        tile[r][tx] = src[(size_t)(p0 + r) * 1024 + f0 + tx];
    __syncthreads();
    for (int r = ty; r < 32; r += 8)
        dst[(size_t)(f0 + r) * 4096 + p0 + tx] = (bf16_t)tile[tx][r];
}

// C[M,N] = A[M,K] @ BT[N,K]^T (bf16, K-major). 128x128 tile, BK=32.
// MODE 0: store C fp32.  MODE 3: store C bf16 in blocked layout
//   Gblk[row/32][col][row%32]  (requires N==1024).
template<int MODE>
__global__ __launch_bounds__(256) void gemm_bt(
    const bf16_t* __restrict__ A, const bf16_t* __restrict__ BT,
    int M, int N, int K,
    float* __restrict__ Cf, bf16_t* __restrict__ Cb)
{
    __shared__ bf16_t As[128 * 32];
    __shared__ bf16_t Bs[128 * 32];
    const int tid  = threadIdx.x;
    const int n0   = blockIdx.x * 128;
    const int m0   = blockIdx.y * 128;
    const int wave = tid >> 6;
    const int lane = tid & 63;
    const int wm   = (wave >> 1) * 64;
    const int wn   = (wave & 1) * 64;
    const int r0   = tid >> 2;
    const int kc   = (tid & 3) * 8;
    const int lr   = lane >> 4;
    const int lc   = lane & 15;

    f32x4 acc[4][4] = {};
    const size_t arow0 = (size_t)(m0 + r0) * K;
    const size_t arow1 = (size_t)(m0 + 64 + r0) * K;
    const size_t brow0 = (size_t)(n0 + r0) * K;
    const size_t brow1 = (size_t)(n0 + 64 + r0) * K;

    for (int k0 = 0; k0 < K; k0 += 32) {
        async_ld16(A + arow0 + k0 + kc, &As[(size_t)tid * 8]);
        async_ld16(A + arow1 + k0 + kc, &As[(size_t)(tid + 256) * 8]);
        async_ld16(BT + brow0 + k0 + kc, &Bs[(size_t)tid * 8]);
        async_ld16(BT + brow1 + k0 + kc, &Bs[(size_t)(tid + 256) * 8]);
        __syncthreads();
        bf16x8 af[4], bv[4];
#pragma unroll
        for (int i = 0; i < 4; ++i) {
            af[i] = *(const bf16x8*)&As[(wm + i * 16 + lc) * 32 + lr * 8];
            bv[i] = *(const bf16x8*)&Bs[(wn + i * 16 + lc) * 32 + lr * 8];
        }
#pragma unroll
        for (int i = 0; i < 4; ++i)
#pragma unroll
            for (int j = 0; j < 4; ++j)
                acc[i][j] = __builtin_amdgcn_mfma_f32_16x16x32_bf16(af[i], bv[j], acc[i][j], 0, 0, 0);
        __syncthreads();
    }

    // C/D layout: col = lane&15, row = (lane>>4)*4 + reg
#pragma unroll
    for (int i = 0; i < 4; ++i)
#pragma unroll
        for (int t = 0; t < 4; ++t) {
            const int row = m0 + wm + i * 16 + lr * 4 + t;
#pragma unroll
            for (int j = 0; j < 4; ++j) {
                const int col = n0 + wn + j * 16 + lc;
                if constexpr (MODE == 0) {
                    Cf[(size_t)row * N + col] = acc[i][j][t];
                } else {
                    Cb[(size_t)(((row >> 5) << 10) + col) * 32 + (row & 31)] =
                        (bf16_t)acc[i][j][t];
                }
            }
        }
}

// Split-F persistent LCA (cooperative). 256 blocks x 1024 thr, 1 block/CU.
// Block (rg = bid>>1, h = bid&1): rows rg*32..+32, feature cols h*512..+512.
// Wave wc in [0,16): 2 m-tiles (rows 0-15,16-31) x 2 n-tiles (cols wc*32..+32).
// G-read per CU per step: 1 MB (vs 2 MB before) -> halves the L2-stream bound.
// act LDS 32x1024 bf16 (64 KB, swizzled); exs fragments 64 KB; total 128 KB.
// U/M/V 48 f32 AGPR + acc 16; partner act halves exchanged via global X
// (double-buffered) + grid.sync() per step.
__global__ __launch_bounds__(1024) __attribute__((amdgpu_waves_per_eu(4, 4)))
void lca_coop(
    const bf16_t* __restrict__ Gblk, const float* __restrict__ excite,
    float* __restrict__ actsf, bf16_t* __restrict__ actbf,
    bf16_t* __restrict__ X0, bf16_t* __restrict__ X1)
{
    __shared__ bf16_t act[32 * 1024];   // 64 KB, swizzled rows of 1024 feats
    __shared__ f32x4  exsv[4 * 1024];   // 64 KB, exsv[q*1024 + tid]
    const int tid  = threadIdx.x;
    const int bid  = blockIdx.x;
    const int h    = bid & 1;
    const int rg   = bid >> 1;
    const int m0   = rg * 32;
    const int wave = tid >> 6;
    const int lane = tid & 63;
    const int lr   = lane >> 4;
    const int lc   = lane & 15;
    const int c0   = h * 512 + wave * 32;   // wave's first feature col

    // zero act (act for step 1 is 0)
    for (int i = tid; i < 32 * 1024 / 8; i += 1024) {
        bf16x8 z = {};
        *(bf16x8*)&act[i * 8] = z;
    }
    // stage excite into per-thread fragment layout (one-time gather)
#pragma unroll
    for (int mt = 0; mt < 2; ++mt)
#pragma unroll
        for (int nt = 0; nt < 2; ++nt) {
            f32x4 e;
#pragma unroll
            for (int t = 0; t < 4; ++t)
                e[t] = excite[(size_t)(m0 + mt * 16 + lr * 4 + t) * 1024 +
                              c0 + nt * 16 + lc];
            exsv[(mt * 2 + nt) * 1024 + tid] = e;
        }
    __syncthreads();

    // AGPR-resident state
    float Ua[2][2][4], Ma[2][2][4], Va[2][2][4];
#pragma unroll
    for (int mt = 0; mt < 2; ++mt)
#pragma unroll
        for (int nt = 0; nt < 2; ++nt)
#pragma unroll
            for (int t = 0; t < 4; ++t) {
                ag_write(Ua[mt][nt][t], 0.0f);
                ag_write(Ma[mt][nt][t], 0.0f);
                ag_write(Va[mt][nt][t], 0.0f);
            }

    const int lcx   = lc & 7;
    const int a0b   = lc * 1024;            // act row lc      (m-tile 0)
    const int a1b   = (16 + lc) * 1024;     // act row 16+lc   (m-tile 1)
    const bf16_t* gpt = Gblk + (((c0 + lc) << 5) + lr * 8);
    const size_t slab_w = ((size_t)(rg * 2 + h)) << 14;        // own 16K elems
    const size_t slab_r = ((size_t)(rg * 2 + (h ^ 1))) << 14;  // partner
    const int hofs_w = h * 512, hofs_r = (h ^ 1) * 512;

    cg::grid_group grid = cg::this_grid();

    const float lrate = 0.1f, b1 = 0.9f, b2 = 0.999f, eps = 1e-8f;
    const float wdmul = 1.0f - lrate * 1e-2f;
    float pb1 = 1.0f, pb2 = 1.0f;

    for (int step = 1; step <= 50; ++step) {
        pb1 *= b1; pb2 *= b2;
        const float inv1 = 1.0f / (1.0f - pb1);
        const float inv2 = 1.0f / (1.0f - pb2);

        f32x4 acc[2][2] = {};
        const bf16_t* gp = gpt;
#pragma unroll 1
        for (int kcb = 0; kcb < 32; ++kcb) {
            const int su = ((kcb * 4 + lr) ^ lcx) << 3;
            const bf16x8 a0 = *(const bf16x8*)&act[a0b + su];
            const bf16x8 a1 = *(const bf16x8*)&act[a1b + su];
            const bf16x8 b0 = *(const bf16x8*)(gp);
            const bf16x8 b1v = *(const bf16x8*)(gp + 512);
            acc[0][0] = __builtin_amdgcn_mfma_f32_16x16x32_bf16(a0, b0,  acc[0][0], 0, 0, 0);
            acc[0][1] = __builtin_amdgcn_mfma_f32_16x16x32_bf16(a0, b1v, acc[0][1], 0, 0, 0);
            acc[1][0] = __builtin_amdgcn_mfma_f32_16x16x32_bf16(a1, b0,  acc[1][0], 0, 0, 0);
            acc[1][1] = __builtin_amdgcn_mfma_f32_16x16x32_bf16(a1, b1v, acc[1][1], 0, 0, 0);
            gp += 32768;
        }
        __syncthreads();   // all waves done reading act

#pragma unroll
        for (int mt = 0; mt < 2; ++mt)
#pragma unroll
            for (int nt = 0; nt < 2; ++nt) {
                const f32x4 ex4 = exsv[(mt * 2 + nt) * 1024 + tid];
#pragma unroll
                for (int t = 0; t < 4; ++t) {
                    const int row = mt * 16 + lr * 4 + t;
                    const int col = c0 + nt * 16 + lc;
                    const float uold = ag_read(Ua[mt][nt][t]);
                    const float mold = ag_read(Ma[mt][nt][t]);
                    const float vold = ag_read(Va[mt][nt][t]);
                    const float aold = fmaxf(uold - 0.25f, 0.0f);
                    const float g    = uold - ex4[t] + acc[mt][nt][t] - aold;
                    const float mn   = b1 * mold + (1.0f - b1) * g;
                    const float vn   = b2 * vold + (1.0f - b2) * g * g;
                    float un = uold * wdmul;
                    un -= lrate * (mn * inv1) / (sqrtf(vn * inv2) + eps);
                    ag_write(Ua[mt][nt][t], un);
                    ag_write(Ma[mt][nt][t], mn);
                    ag_write(Va[mt][nt][t], vn);
                    const float an = fmaxf(un - 0.25f, 0.0f);
                    const int su2 = (col >> 3) ^ (row & 7);
                    act[row * 1024 + (su2 << 3) + (col & 7)] = (bf16_t)an;
                }
            }
        __syncthreads();   // own-half LDS image complete

        if (step < 50) {
            bf16_t* Xw = (step & 1) ? X1 : X0;
            // own half LDS image -> X (coalesced b128; the swizzled half-image
            // of each row is a contiguous 1 KB range: units [h*64, h*64+64))
#pragma unroll
            for (int i2 = 0; i2 < 2; ++i2) {
                const int i = tid + i2 * 1024;
                const int r = i >> 6, c = i & 63;
                *(bf16x8*)(Xw + slab_w + (size_t)i * 8) =
                    *(const bf16x8*)&act[r * 1024 + hofs_w + c * 8];
            }
            __threadfence();
            grid.sync();
            // partner half X -> LDS
#pragma unroll
            for (int i2 = 0; i2 < 2; ++i2) {
                const int i = tid + i2 * 1024;
                const int r = i >> 6, c = i & 63;
                *(bf16x8*)&act[r * 1024 + hofs_r + c * 8] =
                    *(const bf16x8*)(Xw + slab_r + (size_t)i * 8);
            }
            __syncthreads();   // partner half visible to all waves
        }
    }

    // final outputs: act_50 = relu(u_50 - 0.25) from AGPR state
#pragma unroll
    for (int mt = 0; mt < 2; ++mt)
#pragma unroll
        for (int nt = 0; nt < 2; ++nt)
#pragma unroll
            for (int t = 0; t < 4; ++t) {
                const int row = m0 + mt * 16 + lr * 4 + t;
                const int col = c0 + nt * 16 + lc;
                const float an = fmaxf(ag_read(Ua[mt][nt][t]) - 0.25f, 0.0f);
                actsf[(size_t)row * 1024 + col] = an;
                actbf[(size_t)row * 1024 + col] = (bf16_t)an;
            }
}

extern "C" void kernel_launch(void* const* d_in, const int* in_sizes, int n_in,
                              void* d_out, int out_size, void* d_ws, size_t ws_size,
                              hipStream_t stream)
{
    const float* images  = (const float*)d_in[0];   // [4096, 4096] (B x P)
    const float* filters = (const float*)d_in[1];   // [4096, 1024] (P x F)
    float* out = (float*)d_out;

    constexpr int B = 4096, P = 4096, F = 1024;
    constexpr size_t BF = (size_t)B * F;   // 4M elems
    constexpr size_t BP = (size_t)B * P;   // 16M elems

    // d_out (80 MB) time-shared:
    //   out[0 : 8M floats)   : xbf (16M bf16)          -> recon overwrites later
    //   out[8M : 12M floats) : excite fp32             -> recon overwrites later
    //   out[16M : 20M floats): acts output (persistent kernel writes it)
    bf16_t* xbf    = (bf16_t*)out;
    float*  excite = out + 2 * BF;
    float*  actsf  = out + BP;

    // d_ws (18 MB): w0 = phiT -> X0 -> actbf ; Gblk (2 MB) ; phibf region = X1.
    // X0 (w0) last read at start of step 49; actbf written only after the last
    // grid.sync (end of step 49) -> no overlap. phibf converted after lca.
    bf16_t* w0    = (bf16_t*)d_ws;
    bf16_t* Gblk  = w0 + BF;               // +8 MB
    bf16_t* phibf = w0 + BF + BF / 4;      // +10 MB

    dim3 blk(256);
    // 1. x -> bf16
    cvt_bf16<<<(unsigned)(BP / 4 / 256), blk, 0, stream>>>(images, xbf, (long)BP);
    // 2. PhiT bf16 [F,P]
    transpose_cvt<<<dim3(F / 32, P / 32), dim3(32, 8), 0, stream>>>(filters, w0);
    // 3. excite = x @ Phi  (A=xbf [B,P], BT=phiT [F,P]) -> fp32 [B,F]
    gemm_bt<0><<<dim3(F / 128, B / 128), blk, 0, stream>>>(
        xbf, w0, B, F, P, excite, nullptr);
    // 4. G = PhiT @ Phi -> blocked bf16 Gblk[k/32][n][k%32]
    gemm_bt<3><<<dim3(F / 128, F / 128), blk, 0, stream>>>(
        w0, w0, F, F, P, nullptr, Gblk);
    // 5. 50 LCA/AdamW steps, split-F cooperative. acts fp32 (d_out) + actbf (w0).
    {
        const bf16_t* kGblk   = Gblk;
        const float*  kExcite = excite;
        float*        kActsf  = actsf;
        bf16_t*       kActbf  = w0;
        bf16_t*       kX0     = w0;        // 8 MB (time-shared with actbf)
        bf16_t*       kX1     = phibf;     // 8 MB (phibf converted after lca)
        void* kargs[] = { (void*)&kGblk, (void*)&kExcite, (void*)&kActsf,
                          (void*)&kActbf, (void*)&kX0, (void*)&kX1 };
        hipLaunchCooperativeKernel((void*)lca_coop, dim3(256), dim3(1024),
                                   kargs, 0, stream);
    }
    // 6. Phi -> bf16 [P,F]
    cvt_bf16<<<(unsigned)(BF / 4 / 256), blk, 0, stream>>>(filters, phibf, (long)BF);
    // 7. recon = acts @ Phi^T (A=actbf [B,F], BT=phibf [P,F]) -> fp32 [B,P]
    gemm_bt<0><<<dim3(P / 128, B / 128), blk, 0, stream>>>(
        w0, phibf, B, P, F, out, nullptr);
}

// Round 7
// 1887.854 us; speedup vs baseline: 4.5070x; 4.5070x over previous
//
#include <hip/hip_runtime.h>
#include <math.h>

// B=4096 images, P=4096 pixels, F=1024 filters, 50 AdamW steps.
// Round 12: revert R11's cross-XCD exchange (grid.sync + HBM round trips ->
// 8160us). Back to R10 structure (1860us) + exact zero-chunk skip:
// acc += act_chunk @ G_chunk contributes nothing when the 16x32 act chunk is
// bitwise zero -> skip the 4 G loads + 4 MFMAs (wave-uniform via __any).
// Kernel is L2-stream-bound (23.5 B/cy/CU on the 2MB/step G read), so time
// scales with the non-skipped fraction. Steps 1-3 are provably all-zero
// (u ramps from 0 at ~0.1/step toward the 0.25 threshold); synchronized
// LCA oscillation on uniform data likely zeroes more. Skip is exact ->
// bit-identical outputs.

typedef __bf16 bf16_t;
typedef __bf16 bf16x8 __attribute__((ext_vector_type(8)));
typedef __bf16 bf16x4 __attribute__((ext_vector_type(4)));
typedef float f32x4 __attribute__((ext_vector_type(4)));
typedef unsigned int u32x4 __attribute__((ext_vector_type(4)));

__device__ __forceinline__ void async_ld16(const void* g, void* l) {
    __builtin_amdgcn_global_load_lds(
        (const __attribute__((address_space(1))) void*)g,
        (__attribute__((address_space(3))) void*)l, 16, 0, 0);
}

// AGPR stash: long-lived per-thread state in the accumulator half of the
// unified register file (arch half capped at 64 regs at 4 waves/EU).
__device__ __forceinline__ float ag_read(const float& a_) {
    float v;
    asm("v_accvgpr_read_b32 %0, %1" : "=v"(v) : "a"(a_));
    return v;
}
__device__ __forceinline__ void ag_write(float& a_, float v) {
    asm("v_accvgpr_write_b32 %0, %1" : "=a"(a_) : "v"(v));
}

__global__ void cvt_bf16(const float* __restrict__ x, bf16_t* __restrict__ y, long n) {
    long i = ((long)blockIdx.x * blockDim.x + threadIdx.x) * 4;
    if (i + 3 < n) {
        float4 f = *(const float4*)(x + i);
        bf16x4 o = { (bf16_t)f.x, (bf16_t)f.y, (bf16_t)f.z, (bf16_t)f.w };
        *(bf16x4*)(y + i) = o;
    }
}

// PhiT[f][p] = Phi[p][f], fp32 -> bf16.  Phi is [4096,1024].
__global__ void transpose_cvt(const float* __restrict__ src, bf16_t* __restrict__ dst) {
    __shared__ float tile[32][33];
    const int f0 = blockIdx.x * 32;
    const int p0 = blockIdx.y * 32;
    const int tx = threadIdx.x, ty = threadIdx.y;
    for (int r = ty; r < 32; r += 8)
        tile[r][tx] = src[(size_t)(p0 + r) * 1024 + f0 + tx];
    __syncthreads();
    for (int r = ty; r < 32; r += 8)
        dst[(size_t)(f0 + r) * 4096 + p0 + tx] = (bf16_t)tile[tx][r];
}

// C[M,N] = A[M,K] @ BT[N,K]^T (bf16, K-major). 128x128 tile, BK=32.
// MODE 0: store C fp32.  MODE 3: store C bf16 in blocked layout
//   Gblk[row/32][col][row%32]  (requires N==1024).
template<int MODE>
__global__ __launch_bounds__(256) void gemm_bt(
    const bf16_t* __restrict__ A, const bf16_t* __restrict__ BT,
    int M, int N, int K,
    float* __restrict__ Cf, bf16_t* __restrict__ Cb)
{
    __shared__ bf16_t As[128 * 32];
    __shared__ bf16_t Bs[128 * 32];
    const int tid  = threadIdx.x;
    const int n0   = blockIdx.x * 128;
    const int m0   = blockIdx.y * 128;
    const int wave = tid >> 6;
    const int lane = tid & 63;
    const int wm   = (wave >> 1) * 64;
    const int wn   = (wave & 1) * 64;
    const int r0   = tid >> 2;
    const int kc   = (tid & 3) * 8;
    const int lr   = lane >> 4;
    const int lc   = lane & 15;

    f32x4 acc[4][4] = {};
    const size_t arow0 = (size_t)(m0 + r0) * K;
    const size_t arow1 = (size_t)(m0 + 64 + r0) * K;
    const size_t brow0 = (size_t)(n0 + r0) * K;
    const size_t brow1 = (size_t)(n0 + 64 + r0) * K;

    for (int k0 = 0; k0 < K; k0 += 32) {
        async_ld16(A + arow0 + k0 + kc, &As[(size_t)tid * 8]);
        async_ld16(A + arow1 + k0 + kc, &As[(size_t)(tid + 256) * 8]);
        async_ld16(BT + brow0 + k0 + kc, &Bs[(size_t)tid * 8]);
        async_ld16(BT + brow1 + k0 + kc, &Bs[(size_t)(tid + 256) * 8]);
        __syncthreads();
        bf16x8 af[4], bv[4];
#pragma unroll
        for (int i = 0; i < 4; ++i) {
            af[i] = *(const bf16x8*)&As[(wm + i * 16 + lc) * 32 + lr * 8];
            bv[i] = *(const bf16x8*)&Bs[(wn + i * 16 + lc) * 32 + lr * 8];
        }
#pragma unroll
        for (int i = 0; i < 4; ++i)
#pragma unroll
            for (int j = 0; j < 4; ++j)
                acc[i][j] = __builtin_amdgcn_mfma_f32_16x16x32_bf16(af[i], bv[j], acc[i][j], 0, 0, 0);
        __syncthreads();
    }

    // C/D layout: col = lane&15, row = (lane>>4)*4 + reg
#pragma unroll
    for (int i = 0; i < 4; ++i)
#pragma unroll
        for (int t = 0; t < 4; ++t) {
            const int row = m0 + wm + i * 16 + lr * 4 + t;
#pragma unroll
            for (int j = 0; j < 4; ++j) {
                const int col = n0 + wn + j * 16 + lc;
                if constexpr (MODE == 0) {
                    Cf[(size_t)row * N + col] = acc[i][j][t];
                } else {
                    Cb[(size_t)(((row >> 5) << 10) + col) * 32 + (row & 31)] =
                        (bf16_t)acc[i][j][t];
                }
            }
        }
}

// Persistent LCA: each block owns 16 rows for all 50 steps.
// 1024 threads = 16 waves; wave w covers cols [w*64, w*64+64) (4 n-tiles).
// State u,m,v (48 f32/thread) + acc (16) in AGPRs (64 = full accum half);
// excite in LDS as per-thread f32x4 fragments (64 KB, conflict-free);
// act bf16 in LDS (32 KB, swizzled); G streamed from L2 via blocked layout
// Gblk[k/32][n][k%32]. Zero-chunk skip: if the wave's 16x32 act chunk is
// bitwise zero, its 4 G-loads + 4 MFMAs are skipped (exact; wave-uniform).
__global__ __launch_bounds__(1024) __attribute__((amdgpu_waves_per_eu(4, 4)))
void lca_persistent(
    const bf16_t* __restrict__ Gblk, const float* __restrict__ excite,
    float* __restrict__ actsf, bf16_t* __restrict__ actbf)
{
    __shared__ bf16_t act[16 * 1024];   // 32 KB, swizzled
    __shared__ f32x4  exsv[4096];       // 64 KB, exsv[j*1024 + tid]
    const int tid  = threadIdx.x;
    const int m0   = blockIdx.x * 16;
    const int wave = tid >> 6;
    const int lane = tid & 63;
    const int lr   = lane >> 4;
    const int lc   = lane & 15;
    const int wn   = wave * 64;

    // zero act buffer (act_1 = relu(0 - 0.25) = 0)
    for (int i = tid; i < 16 * 1024 / 8; i += 1024) {
        bf16x8 z = {};
        *(bf16x8*)&act[i * 8] = z;
    }
    // stage excite into per-thread fragment layout (one-time gather)
#pragma unroll
    for (int j = 0; j < 4; ++j) {
        f32x4 e;
#pragma unroll
        for (int t = 0; t < 4; ++t)
            e[t] = excite[(size_t)(m0 + lr * 4 + t) * 1024 + wn + j * 16 + lc];
        exsv[j * 1024 + tid] = e;
    }
    __syncthreads();

    // AGPR-resident state (48 f32/thread)
    float Ua[4][4], Ma[4][4], Va[4][4];
#pragma unroll
    for (int j = 0; j < 4; ++j)
#pragma unroll
        for (int t = 0; t < 4; ++t) {
            ag_write(Ua[j][t], 0.0f);
            ag_write(Ma[j][t], 0.0f);
            ag_write(Va[j][t], 0.0f);
        }

    // per-thread invariant offsets
    const int aoff = lc * 1024;       // act row base (elements)
    const int lcx  = lc & 7;
    const bf16_t* gpt = Gblk + (((wn + lc) << 5) + lr * 8);

    const float lrate = 0.1f, b1 = 0.9f, b2 = 0.999f, eps = 1e-8f;
    const float wdmul = 1.0f - lrate * 1e-2f;
    float pb1 = 1.0f, pb2 = 1.0f;

    for (int step = 1; step <= 50; ++step) {
        pb1 *= b1; pb2 *= b2;
        const float inv1 = 1.0f / (1.0f - pb1);
        const float inv2 = 1.0f / (1.0f - pb2);

        f32x4 acc[4] = {};
        const bf16_t* gp = gpt;
#pragma unroll 1
        for (int kcb = 0; kcb < 32; ++kcb) {
            // A-fragment: act[m = lc][k = kcb*32 + lr*8 + 0..7], swizzled
            const int su = ((kcb * 4 + lr) ^ lcx) << 3;
            const bf16x8 a = *(const bf16x8*)&act[aoff + su];
            const u32x4 av = __builtin_bit_cast(u32x4, a);
            if (__any((av[0] | av[1] | av[2] | av[3]) != 0u)) {
                const bf16x8 b0  = *(const bf16x8*)(gp);
                const bf16x8 b1v = *(const bf16x8*)(gp + 512);
                const bf16x8 b2v = *(const bf16x8*)(gp + 1024);
                const bf16x8 b3v = *(const bf16x8*)(gp + 1536);
                acc[0] = __builtin_amdgcn_mfma_f32_16x16x32_bf16(a, b0,  acc[0], 0, 0, 0);
                acc[1] = __builtin_amdgcn_mfma_f32_16x16x32_bf16(a, b1v, acc[1], 0, 0, 0);
                acc[2] = __builtin_amdgcn_mfma_f32_16x16x32_bf16(a, b2v, acc[2], 0, 0, 0);
                acc[3] = __builtin_amdgcn_mfma_f32_16x16x32_bf16(a, b3v, acc[3], 0, 0, 0);
            }
            gp += 32768;
        }
        __syncthreads();   // all waves done reading act

#pragma unroll
        for (int j = 0; j < 4; ++j) {
            const f32x4 ex4 = exsv[j * 1024 + tid];
#pragma unroll
            for (int t = 0; t < 4; ++t) {
                const int row = lr * 4 + t;
                const int col = wn + j * 16 + lc;
                const float uold = ag_read(Ua[j][t]);
                const float mold = ag_read(Ma[j][t]);
                const float vold = ag_read(Va[j][t]);
                const float aold = fmaxf(uold - 0.25f, 0.0f);
                const float g    = uold - ex4[t] + acc[j][t] - aold;
                const float mn   = b1 * mold + (1.0f - b1) * g;
                const float vn   = b2 * vold + (1.0f - b2) * g * g;
                float un = uold * wdmul;
                un -= lrate * (mn * inv1) / (sqrtf(vn * inv2) + eps);
                ag_write(Ua[j][t], un);
                ag_write(Ma[j][t], mn);
                ag_write(Va[j][t], vn);
                const float an = fmaxf(un - 0.25f, 0.0f);
                const int su2 = (col >> 3) ^ (row & 7);
                act[row * 1024 + (su2 << 3) + (col & 7)] = (bf16_t)an;
            }
        }
        __syncthreads();   // act ready for next step
    }

    // final outputs: act_50 = relu(u_50 - 0.25), recomputed from AGPR state
#pragma unroll
    for (int j = 0; j < 4; ++j)
#pragma unroll
        for (int t = 0; t < 4; ++t) {
            const int row = lr * 4 + t;
            const int col = wn + j * 16 + lc;
            const float an = fmaxf(ag_read(Ua[j][t]) - 0.25f, 0.0f);
            actsf[(size_t)(m0 + row) * 1024 + col] = an;
            actbf[(size_t)(m0 + row) * 1024 + col] = (bf16_t)an;
        }
}

extern "C" void kernel_launch(void* const* d_in, const int* in_sizes, int n_in,
                              void* d_out, int out_size, void* d_ws, size_t ws_size,
                              hipStream_t stream)
{
    const float* images  = (const float*)d_in[0];   // [4096, 4096] (B x P)
    const float* filters = (const float*)d_in[1];   // [4096, 1024] (P x F)
    float* out = (float*)d_out;

    constexpr int B = 4096, P = 4096, F = 1024;
    constexpr size_t BF = (size_t)B * F;   // 4M elems
    constexpr size_t BP = (size_t)B * P;   // 16M elems

    // d_out (80 MB) time-shared:
    //   out[0 : 8M floats)   : xbf (16M bf16)          -> recon overwrites later
    //   out[8M : 12M floats) : excite fp32             -> recon overwrites later
    //   out[16M : 20M floats): acts output (persistent kernel writes it)
    bf16_t* xbf    = (bf16_t*)out;
    float*  excite = out + 2 * BF;
    float*  actsf  = out + BP;

    // d_ws (18 MB): w0 = phiT (8 MB) then actbf ; Gblk (2 MB) ; phibf (8 MB)
    bf16_t* w0    = (bf16_t*)d_ws;
    bf16_t* Gblk  = w0 + BF;               // +8 MB
    bf16_t* phibf = w0 + BF + BF / 4;      // +10 MB

    dim3 blk(256);
    // 1. x -> bf16
    cvt_bf16<<<(unsigned)(BP / 4 / 256), blk, 0, stream>>>(images, xbf, (long)BP);
    // 2. PhiT bf16 [F,P]
    transpose_cvt<<<dim3(F / 32, P / 32), dim3(32, 8), 0, stream>>>(filters, w0);
    // 3. excite = x @ Phi  (A=xbf [B,P], BT=phiT [F,P]) -> fp32 [B,F]
    gemm_bt<0><<<dim3(F / 128, B / 128), blk, 0, stream>>>(
        xbf, w0, B, F, P, excite, nullptr);
    // 4. G = PhiT @ Phi -> blocked bf16 Gblk[k/32][n][k%32]
    gemm_bt<3><<<dim3(F / 128, F / 128), blk, 0, stream>>>(
        w0, w0, F, F, P, nullptr, Gblk);
    // 5. 50 LCA/AdamW steps, persistent. Writes acts fp32 (d_out) + actbf (w0).
    lca_persistent<<<dim3(B / 16), dim3(1024), 0, stream>>>(Gblk, excite, actsf, w0);
    // 6. Phi -> bf16 [P,F]
    cvt_bf16<<<(unsigned)(BF / 4 / 256), blk, 0, stream>>>(filters, phibf, (long)BF);
    // 7. recon = acts @ Phi^T (A=actbf [B,F], BT=phibf [P,F]) -> fp32 [B,P]
    gemm_bt<0><<<dim3(P / 128, B / 128), blk, 0, stream>>>(
        w0, phibf, B, P, F, out, nullptr);
}